// Round 8
// baseline (158.144 us; speedup 1.0000x reference)
//
#include <hip/hip_runtime.h>
#include <math.h>

#define BB 64
#define MM 128
#define DDIM 2048
#define KK 32
#define NDC 16                   // d-chunks for k_vlad (128-wide each)
#define OUTROW (DDIM + KK*DDIM)  // 67584

typedef __attribute__((ext_vector_type(8))) short bf16x8;
typedef __attribute__((ext_vector_type(4))) float f32x4;

// float -> bf16 RNE (inputs finite; no NaN handling needed)
__device__ __forceinline__ short f2bf(float f) {
  unsigned u = __builtin_bit_cast(unsigned, f);
  u += 0x7fffu + ((u >> 16) & 1u);
  return (short)(u >> 16);
}
__device__ __forceinline__ unsigned pack2(float lo, float hi) {
  return (unsigned)(unsigned short)f2bf(lo) | ((unsigned)(unsigned short)f2bf(hi) << 16);
}

// ---------------------------------------------------------------------------
// K0: W fp32 -> bf16 once. 65536 elems, 32 blocks x 256 x 8.
// ---------------------------------------------------------------------------
__global__ __launch_bounds__(256) void k_prep(const float* __restrict__ W,
                                              short* __restrict__ Wb) {
  int i = (blockIdx.x * 256 + threadIdx.x) * 8;
  float4 a = *(const float4*)(W + i);
  float4 b = *(const float4*)(W + i + 4);
  bf16x8 o = {f2bf(a.x), f2bf(a.y), f2bf(a.z), f2bf(a.w),
              f2bf(b.x), f2bf(b.y), f2bf(b.z), f2bf(b.w)};
  *(bf16x8*)(Wb + i) = o;
}

// ---------------------------------------------------------------------------
// K1: fused logits GEMM (bf16 MFMA) + ssq + softmax + mask.
// r7: occupancy 2->4 blocks/CU. The old K-half kept 16 x-float4 + 16
// W-bf16x8 live (~128 VGPR of loads) forcing 116 VGPR / 2 blocks. K-loop
// re-chunked to 4 chunks x 4 steps (live loads ~64 VGPR) under
// __launch_bounds__(256,4): all 512 blocks co-resident, 16 waves/CU to
// hide the ~900cy HBM chunk-waits. MFMA accumulation order over s is
// unchanged -> bit-identical output.
// ---------------------------------------------------------------------------
__global__ __launch_bounds__(256, 4) void k_logits(const float* __restrict__ x,
    const int* __restrict__ lengths, const short* __restrict__ Wb,
    short* __restrict__ aT, float* __restrict__ asum_p) {
  const int t = threadIdx.x, wv = t >> 6, lane = t & 63;
  const int l15 = lane & 15, quad = lane >> 4;
  const int fg = blockIdx.x;           // 0..511
  const int g0 = fg * 16;              // first frame of block
  const int b  = fg >> 3;              // 8 blocks per batch
  const int m0 = (fg & 7) * 16;        // frame offset within batch
  const int len = lengths[b];

  if (m0 >= len) {
    // fully-invalid frame group: a == 0 -> write zeros directly, exit.
    if (t < KK) asum_p[(size_t)fg * KK + t] = 0.f;
    const int zk = t >> 3, zoff = (t & 7) * 2;   // 32 k x 16 m = 1024B
    *(unsigned*)(aT + (size_t)b * KK * MM + (size_t)zk * MM + m0 + zoff) = 0u;
    return;
  }

  const bool av = (m0 + l15) < len;    // lane's frame valid (const over loop)
  const float* xrow = x + (size_t)(g0 + l15) * DDIM + wv * 512 + quad * 8;
  const short* w0   = Wb + l15 * DDIM + wv * 512 + quad * 8;
  const short* w1   = w0 + 16 * DDIM;

  f32x4 c0 = {0.f, 0.f, 0.f, 0.f}, c1 = {0.f, 0.f, 0.f, 0.f};
  float ssq = 0.f;
  #pragma unroll
  for (int h = 0; h < 4; ++h) {        // 4 chunks x 4 steps
    float4 xa[4], xc[4];
    bf16x8 B0[4], B1[4];
    #pragma unroll
    for (int s = 0; s < 4; ++s) {
      const int so = h * 4 + s;
      if (av) {
        xa[s] = *(const float4*)(xrow + so * 32);
        xc[s] = *(const float4*)(xrow + so * 32 + 4);
      } else {
        xa[s] = make_float4(0.f, 0.f, 0.f, 0.f);
        xc[s] = make_float4(0.f, 0.f, 0.f, 0.f);
      }
      B0[s] = *(const bf16x8*)(w0 + so * 32);
      B1[s] = *(const bf16x8*)(w1 + so * 32);
    }
    #pragma unroll
    for (int s = 0; s < 4; ++s) {
      ssq = fmaf(xa[s].x, xa[s].x, ssq); ssq = fmaf(xa[s].y, xa[s].y, ssq);
      ssq = fmaf(xa[s].z, xa[s].z, ssq); ssq = fmaf(xa[s].w, xa[s].w, ssq);
      ssq = fmaf(xc[s].x, xc[s].x, ssq); ssq = fmaf(xc[s].y, xc[s].y, ssq);
      ssq = fmaf(xc[s].z, xc[s].z, ssq); ssq = fmaf(xc[s].w, xc[s].w, ssq);
      bf16x8 A = {f2bf(xa[s].x), f2bf(xa[s].y), f2bf(xa[s].z), f2bf(xa[s].w),
                  f2bf(xc[s].x), f2bf(xc[s].y), f2bf(xc[s].z), f2bf(xc[s].w)};
      c0 = __builtin_amdgcn_mfma_f32_16x16x32_bf16(A, B0[s], c0, 0, 0, 0);
      c1 = __builtin_amdgcn_mfma_f32_16x16x32_bf16(A, B1[s], c1, 0, 0, 0);
    }
  }

  ssq += __shfl_xor(ssq, 16, 64);
  ssq += __shfl_xor(ssq, 32, 64);
  __shared__ float sq[4][16];
  __shared__ float lg[4][16][33];
  if (quad == 0) sq[wv][l15] = ssq;
  // C layout: row(frame) = quad*4+reg, col(k) = l15
  #pragma unroll
  for (int r = 0; r < 4; ++r) {
    lg[wv][quad * 4 + r][l15]      = c0[r];
    lg[wv][quad * 4 + r][16 + l15] = c1[r];
  }
  __syncthreads();

  // 16 threads per frame, 2 clusters each
  const int fr = t >> 4, kk = (t & 15) * 2;
  float s0 = 0.f, s1 = 0.f;
  #pragma unroll
  for (int w = 0; w < 4; ++w) { s0 += lg[w][fr][kk]; s1 += lg[w][fr][kk + 1]; }
  float ss  = sq[0][fr] + sq[1][fr] + sq[2][fr] + sq[3][fr];
  float inv = 1.f / fmaxf(sqrtf(ss), 1e-12f);
  s0 *= inv; s1 *= inv;
  float mx = fmaxf(s0, s1);
  mx = fmaxf(mx, __shfl_xor(mx, 1, 64));
  mx = fmaxf(mx, __shfl_xor(mx, 2, 64));
  mx = fmaxf(mx, __shfl_xor(mx, 4, 64));
  mx = fmaxf(mx, __shfl_xor(mx, 8, 64));
  float e0 = __expf(s0 - mx), e1 = __expf(s1 - mx);
  float se = e0 + e1;
  se += __shfl_xor(se, 1, 64);
  se += __shfl_xor(se, 2, 64);
  se += __shfl_xor(se, 4, 64);
  se += __shfl_xor(se, 8, 64);
  const bool valid = (m0 + fr) < len;
  float rr = valid ? (1.f / se) : 0.f;
  float a0 = e0 * rr, a1 = e1 * rr;

  __syncthreads();                    // done reading lg; reuse for asum
  lg[0][fr][kk] = a0; lg[0][fr][kk + 1] = a1;
  __syncthreads();
  if (t < KK) {
    float s = 0.f;
    #pragma unroll
    for (int f = 0; f < 16; ++f) s += lg[0][f][t];
    asum_p[(size_t)fg * KK + t] = s;
  }
  // a' = a * invn, transposed store [b][k][m]
  short* ap = aT + (size_t)b * KK * MM + m0 + fr;
  ap[(size_t)kk * MM]       = f2bf(a0 * inv);
  ap[(size_t)(kk + 1) * MM] = f2bf(a1 * inv);
}

// ---------------------------------------------------------------------------
// K2: vlad GEMM, fine-split (r6): grid (16 dc, 64 b) = 1024 blocks, 4/CU.
// Unchanged from r6.
// ---------------------------------------------------------------------------
__global__ __launch_bounds__(256, 4) void k_vlad(const float* __restrict__ x,
    const int* __restrict__ lengths, const float* __restrict__ Cc,
    const short* __restrict__ aT, const float* __restrict__ asum_p,
    float* __restrict__ out, float* __restrict__ ssq_part) {
  const int t = threadIdx.x, wv = t >> 6, lane = t & 63;
  const int l15 = lane & 15, quad = lane >> 4;
  const int dc = blockIdx.x, b = blockIdx.y;
  const int dh = wv & 1, mh = wv >> 1;
  const int dwb = dc * 128 + dh * 64;   // wave d-base (64 wide)
  const int mb  = mh * 64;              // wave m-base (64 frames)
  const int len = lengths[b];

  __shared__ __attribute__((aligned(16))) char ubuf[20480];
  short (*xbt)[64][40]     = (short(*)[64][40])ubuf;      // [wv][d-loc][m-slot]
  float (*exch)[2][64][20] = (float(*)[2][64][20])ubuf;   // [dh][writer mh][lane][16+pad]
  __shared__ float  asl[KK];
  __shared__ float4 avp[2][16];         // [dh][l15] avg partial of mh=1
  __shared__ float  ssw[4][17];         // [wv][k-local]

  if (t < KK) {
    float s = 0.f;
    #pragma unroll
    for (int p = 0; p < 8; ++p) s += asum_p[(size_t)(b * 8 + p) * KK + t];
    asl[t] = s;
  }

  const float* xb  = x  + (size_t)b * MM * DDIM;
  const short* at0 = aT + (size_t)b * KK * MM + l15 * MM + mb + quad * 8;

  const int q4   = l15 * 4;             // lane's 4 staged d-rows
  const int mrow = quad * 2;            // even m within pass group
  const int keyw = l15 & 3;             // store swizzle key
  const int keyr = (l15 >> 2) & 3;      // read swizzle key

  // ---- preload A-frags (L2-hot) ----
  bf16x8 A0[2], A1[2];
  #pragma unroll
  for (int ms = 0; ms < 2; ++ms) {
    A0[ms] = *(const bf16x8*)(at0 + ms * 32);
    A1[ms] = *(const bf16x8*)(at0 + 16 * MM + ms * 32);
  }

  // ---- preload all x (16 independent float4 loads in flight, masked) ----
  float4 v0[8], v1[8];
  #pragma unroll
  for (int ms = 0; ms < 2; ++ms) {
    #pragma unroll
    for (int p = 0; p < 4; ++p) {
      const int m = mb + ms * 32 + p * 8 + mrow;
      const float* xr = xb + (size_t)m * DDIM + dwb + q4;
      v0[ms * 4 + p] = (m < len) ? *(const float4*)xr
                                 : make_float4(0.f, 0.f, 0.f, 0.f);
      v1[ms * 4 + p] = (m + 1 < len) ? *(const float4*)(xr + DDIM)
                                     : make_float4(0.f, 0.f, 0.f, 0.f);
    }
  }

  // avgpool partial over this wave's m-half (zero-fill makes masking free)
  float avg[4] = {0.f, 0.f, 0.f, 0.f};
  #pragma unroll
  for (int i = 0; i < 8; ++i) {
    avg[0] += v0[i].x + v1[i].x;
    avg[1] += v0[i].y + v1[i].y;
    avg[2] += v0[i].z + v1[i].z;
    avg[3] += v0[i].w + v1[i].w;
  }
  #pragma unroll
  for (int c = 0; c < 4; ++c) {
    avg[c] += __shfl_xor(avg[c], 16, 64);
    avg[c] += __shfl_xor(avg[c], 32, 64);
  }
  if (mh == 1 && quad == 0)
    avp[dh][l15] = make_float4(avg[0], avg[1], avg[2], avg[3]);

  f32x4 acc0[4], acc1[4];
  #pragma unroll
  for (int nt = 0; nt < 4; ++nt) {
    acc0[nt] = (f32x4){0.f, 0.f, 0.f, 0.f};
    acc1[nt] = (f32x4){0.f, 0.f, 0.f, 0.f};
  }

  #pragma unroll
  for (int ms = 0; ms < 2; ++ms) {
    #pragma unroll
    for (int p = 0; p < 4; ++p) {
      const int i = ms * 4 + p;
      const int mls = (p ^ keyw) * 8 + mrow;  // swizzled m-slot
      *(unsigned*)&xbt[wv][q4 + 0][mls] = pack2(v0[i].x, v1[i].x);
      *(unsigned*)&xbt[wv][q4 + 1][mls] = pack2(v0[i].y, v1[i].y);
      *(unsigned*)&xbt[wv][q4 + 2][mls] = pack2(v0[i].z, v1[i].z);
      *(unsigned*)&xbt[wv][q4 + 3][mls] = pack2(v0[i].w, v1[i].w);
    }
    // wave-private tile: same-wave DS ordering is program order
    #pragma unroll
    for (int nt = 0; nt < 4; ++nt) {
      bf16x8 B = *(const bf16x8*)&xbt[wv][nt * 16 + l15][(quad ^ keyr) * 8];
      acc0[nt] = __builtin_amdgcn_mfma_f32_16x16x32_bf16(A0[ms], B, acc0[nt], 0, 0, 0);
      acc1[nt] = __builtin_amdgcn_mfma_f32_16x16x32_bf16(A1[ms], B, acc1[nt], 0, 0, 0);
    }
  }

  // wave-uniform k-split: keep kt==mh, donate the other half
  f32x4 keep[4], give[4];
  if (mh == 0) {
    #pragma unroll
    for (int nt = 0; nt < 4; ++nt) { keep[nt] = acc0[nt]; give[nt] = acc1[nt]; }
  } else {
    #pragma unroll
    for (int nt = 0; nt < 4; ++nt) { keep[nt] = acc1[nt]; give[nt] = acc0[nt]; }
  }

  __syncthreads();   // all xbt reads done (union safe); avp, asl visible
  #pragma unroll
  for (int nt = 0; nt < 4; ++nt)
    *(f32x4*)&exch[dh][mh][lane][nt * 4] = give[nt];

  // avgpool finish (mh=0 waves own the write)
  if (mh == 0 && quad == 0) {
    float4 pa = avp[dh][l15];
    float rl = 1.f / (float)len;
    *(float4*)(out + (size_t)b * OUTROW + dwb + q4) =
        make_float4((avg[0] + pa.x) * rl, (avg[1] + pa.y) * rl,
                    (avg[2] + pa.z) * rl, (avg[3] + pa.w) * rl);
  }

  __syncthreads();   // exch stores visible
  #pragma unroll
  for (int nt = 0; nt < 4; ++nt)
    keep[nt] += *(const f32x4*)&exch[dh][1 - mh][lane][nt * 4];

  // residual + ssq for this wave's 16 k x 64 d
  float* orow = out + (size_t)b * OUTROW + DDIM;
  #pragma unroll
  for (int r = 0; r < 4; ++r) {
    const int k = mh * 16 + quad * 4 + r;
    const float as = asl[k];
    float sqv = 0.f;
    #pragma unroll
    for (int nt = 0; nt < 4; ++nt) {
      const int d = dwb + nt * 16 + l15;
      float v = keep[nt][r] - as * Cc[(size_t)k * DDIM + d];
      orow[(size_t)k * DDIM + d] = v;
      sqv = fmaf(v, v, sqv);
    }
    sqv += __shfl_xor(sqv, 1, 64);
    sqv += __shfl_xor(sqv, 2, 64);
    sqv += __shfl_xor(sqv, 4, 64);
    sqv += __shfl_xor(sqv, 8, 64);
    if (l15 == 0) ssw[wv][quad * 4 + r] = sqv;
  }
  __syncthreads();
  if (t < KK) {
    const int mt = t >> 4, kl = t & 15;   // waves mt*2 and mt*2+1 hold k=t
    ssq_part[((size_t)dc * BB + b) * KK + t] = ssw[mt * 2][kl] + ssw[mt * 2 + 1][kl];
  }
}

// ---------------------------------------------------------------------------
// K3: fused scales + apply. grid (32 k, 64 b) x 256. NDC=16 partials.
// ---------------------------------------------------------------------------
__global__ __launch_bounds__(256) void k_norm(const float* __restrict__ ssq_part,
    float* __restrict__ out) {
  const int t = threadIdx.x;
  const int k = blockIdx.x;
  const int b = blockIdx.y;
  __shared__ float ssk[32];
  if (t < 32) {
    float sk = 0.f;
    #pragma unroll
    for (int dc = 0; dc < NDC; ++dc)
      sk += ssq_part[((size_t)dc * BB + b) * KK + t];
    ssk[t] = sk;
  }
  __syncthreads();
  float gss = 0.f, iv_own = 0.f;
  #pragma unroll
  for (int kk = 0; kk < 32; ++kk) {
    float nk = sqrtf(ssk[kk]);
    float iv = 1.f / fmaxf(nk, 1e-12f);
    float nn = nk * iv;
    gss += nn * nn;
    if (kk == k) iv_own = iv;
  }
  float sc = iv_own / fmaxf(sqrtf(gss), 1e-12f);
  float* row = out + (size_t)b * OUTROW + DDIM + (size_t)k * DDIM;
  #pragma unroll
  for (int h = 0; h < 2; ++h) {
    float4* p = (float4*)(row + h * 1024 + t * 4);
    float4 v = *p;
    v.x *= sc; v.y *= sc; v.z *= sc; v.w *= sc;
    *p = v;
  }
}

// ---------------------------------------------------------------------------
extern "C" void kernel_launch(void* const* d_in, const int* in_sizes, int n_in,
                              void* d_out, int out_size, void* d_ws, size_t ws_size,
                              hipStream_t stream) {
  const float* x       = (const float*)d_in[0];
  const int*   lengths = (const int*)d_in[1];
  const float* W       = (const float*)d_in[2];
  const float* C       = (const float*)d_in[3];
  float* out = (float*)d_out;

  short* Wb     = (short*)d_ws;                          // 32*2048 shorts
  short* aT     = Wb + (size_t)KK * DDIM;                // 64*32*128 shorts
  float* asum_p = (float*)(aT + (size_t)BB * KK * MM);   // 512*32 floats
  float* ssqp   = asum_p + (size_t)512 * KK;             // 16*64*32 floats

  k_prep  <<<dim3(32),      256, 0, stream>>>(W, Wb);
  k_logits<<<dim3(512),     256, 0, stream>>>(x, lengths, Wb, aT, asum_p);
  k_vlad  <<<dim3(NDC, BB), 256, 0, stream>>>(x, lengths, C, aT, asum_p, out, ssqp);
  k_norm  <<<dim3(KK, BB),  256, 0, stream>>>(ssqp, out);
}

// Round 9
// 143.063 us; speedup vs baseline: 1.1054x; 1.1054x over previous
//
#include <hip/hip_runtime.h>
#include <math.h>

#define BB 64
#define MM 128
#define DDIM 2048
#define KK 32
#define NDC 16                   // d-chunks for k_vlad (128-wide each)
#define OUTROW (DDIM + KK*DDIM)  // 67584

typedef __attribute__((ext_vector_type(8))) short bf16x8;
typedef __attribute__((ext_vector_type(4))) float f32x4;

// float -> bf16 RNE (inputs finite; no NaN handling needed)
__device__ __forceinline__ short f2bf(float f) {
  unsigned u = __builtin_bit_cast(unsigned, f);
  u += 0x7fffu + ((u >> 16) & 1u);
  return (short)(u >> 16);
}
__device__ __forceinline__ unsigned pack2(float lo, float hi) {
  return (unsigned)(unsigned short)f2bf(lo) | ((unsigned)(unsigned short)f2bf(hi) << 16);
}

// ---------------------------------------------------------------------------
// K0: W fp32 -> bf16 once. 65536 elems, 32 blocks x 256 x 8.
// ---------------------------------------------------------------------------
__global__ __launch_bounds__(256) void k_prep(const float* __restrict__ W,
                                              short* __restrict__ Wb) {
  int i = (blockIdx.x * 256 + threadIdx.x) * 8;
  float4 a = *(const float4*)(W + i);
  float4 b = *(const float4*)(W + i + 4);
  bf16x8 o = {f2bf(a.x), f2bf(a.y), f2bf(a.z), f2bf(a.w),
              f2bf(b.x), f2bf(b.y), f2bf(b.z), f2bf(b.w)};
  *(bf16x8*)(Wb + i) = o;
}

// ---------------------------------------------------------------------------
// K1: fused logits GEMM (bf16 MFMA) + ssq + softmax + mask.
// r9: k_logits' grid is FIXED at 512 blocks = 2 blocks/CU — r8's launch_
// bounds(256,4) could never raise residency (the r8 mistake) and its
// chunking halved per-wave MLP. Fix: widen the block to 512 threads
// (8 waves), D split 8 ways (256/wave), per-wave full preload (32 VMEM in
// flight, the r6-proven shape). CU now holds 16 waves with 2x the in-flight
// loads of r6. Softmax phase reworked to 32 threads/frame.
// ---------------------------------------------------------------------------
__global__ __launch_bounds__(512, 4) void k_logits(const float* __restrict__ x,
    const int* __restrict__ lengths, const short* __restrict__ Wb,
    short* __restrict__ aT, float* __restrict__ asum_p) {
  const int t = threadIdx.x, wv = t >> 6, lane = t & 63;
  const int l15 = lane & 15, quad = lane >> 4;
  const int fg = blockIdx.x;           // 0..511
  const int g0 = fg * 16;              // first frame of block
  const int b  = fg >> 3;              // 8 blocks per batch
  const int m0 = (fg & 7) * 16;        // frame offset within batch
  const int len = lengths[b];

  if (m0 >= len) {
    // fully-invalid frame group: a == 0 -> write zeros directly, exit.
    if (t < KK) asum_p[(size_t)fg * KK + t] = 0.f;
    if (t < 256) {
      const int zk = t >> 3, zoff = (t & 7) * 2;   // 32 k x 16 m = 1024B
      *(unsigned*)(aT + (size_t)b * KK * MM + (size_t)zk * MM + m0 + zoff) = 0u;
    }
    return;
  }

  const bool av = (m0 + l15) < len;    // lane's frame valid (const over loop)
  const float* xrow = x + (size_t)(g0 + l15) * DDIM + wv * 256 + quad * 8;
  const short* w0   = Wb + l15 * DDIM + wv * 256 + quad * 8;
  const short* w1   = w0 + 16 * DDIM;

  f32x4 c0 = {0.f, 0.f, 0.f, 0.f}, c1 = {0.f, 0.f, 0.f, 0.f};
  float ssq = 0.f;
  {
    float4 xa[8], xc[8];
    bf16x8 B0[8], B1[8];
    #pragma unroll
    for (int s = 0; s < 8; ++s) {      // full preload: 32 VMEM in flight
      if (av) {
        xa[s] = *(const float4*)(xrow + s * 32);
        xc[s] = *(const float4*)(xrow + s * 32 + 4);
      } else {
        xa[s] = make_float4(0.f, 0.f, 0.f, 0.f);
        xc[s] = make_float4(0.f, 0.f, 0.f, 0.f);
      }
      B0[s] = *(const bf16x8*)(w0 + s * 32);
      B1[s] = *(const bf16x8*)(w1 + s * 32);
    }
    #pragma unroll
    for (int s = 0; s < 8; ++s) {
      ssq = fmaf(xa[s].x, xa[s].x, ssq); ssq = fmaf(xa[s].y, xa[s].y, ssq);
      ssq = fmaf(xa[s].z, xa[s].z, ssq); ssq = fmaf(xa[s].w, xa[s].w, ssq);
      ssq = fmaf(xc[s].x, xc[s].x, ssq); ssq = fmaf(xc[s].y, xc[s].y, ssq);
      ssq = fmaf(xc[s].z, xc[s].z, ssq); ssq = fmaf(xc[s].w, xc[s].w, ssq);
      bf16x8 A = {f2bf(xa[s].x), f2bf(xa[s].y), f2bf(xa[s].z), f2bf(xa[s].w),
                  f2bf(xc[s].x), f2bf(xc[s].y), f2bf(xc[s].z), f2bf(xc[s].w)};
      c0 = __builtin_amdgcn_mfma_f32_16x16x32_bf16(A, B0[s], c0, 0, 0, 0);
      c1 = __builtin_amdgcn_mfma_f32_16x16x32_bf16(A, B1[s], c1, 0, 0, 0);
    }
  }

  ssq += __shfl_xor(ssq, 16, 64);
  ssq += __shfl_xor(ssq, 32, 64);
  __shared__ float sq[8][16];
  __shared__ float lg[8][16][33];
  if (quad == 0) sq[wv][l15] = ssq;
  // C layout: row(frame) = quad*4+reg, col(k) = l15
  #pragma unroll
  for (int r = 0; r < 4; ++r) {
    lg[wv][quad * 4 + r][l15]      = c0[r];
    lg[wv][quad * 4 + r][16 + l15] = c1[r];
  }
  __syncthreads();

  // 32 threads per frame, 1 cluster each
  const int fr = t >> 5, kk = t & 31;
  float s0 = 0.f;
  #pragma unroll
  for (int w = 0; w < 8; ++w) s0 += lg[w][fr][kk];
  float ss = 0.f;
  #pragma unroll
  for (int w = 0; w < 8; ++w) ss += sq[w][fr];
  float inv = 1.f / fmaxf(sqrtf(ss), 1e-12f);
  s0 *= inv;
  float mx = s0;
  mx = fmaxf(mx, __shfl_xor(mx, 1, 32));
  mx = fmaxf(mx, __shfl_xor(mx, 2, 32));
  mx = fmaxf(mx, __shfl_xor(mx, 4, 32));
  mx = fmaxf(mx, __shfl_xor(mx, 8, 32));
  mx = fmaxf(mx, __shfl_xor(mx, 16, 32));
  float e0 = __expf(s0 - mx);
  float se = e0;
  se += __shfl_xor(se, 1, 32);
  se += __shfl_xor(se, 2, 32);
  se += __shfl_xor(se, 4, 32);
  se += __shfl_xor(se, 8, 32);
  se += __shfl_xor(se, 16, 32);
  const bool valid = (m0 + fr) < len;
  float rr = valid ? (1.f / se) : 0.f;
  float a0 = e0 * rr;

  __syncthreads();                    // done reading lg; reuse for asum
  lg[0][fr][kk] = a0;
  __syncthreads();
  if (t < KK) {
    float s = 0.f;
    #pragma unroll
    for (int f = 0; f < 16; ++f) s += lg[0][f][t];
    asum_p[(size_t)fg * KK + t] = s;
  }
  // a' = a * invn, transposed store [b][k][m]
  short* ap = aT + (size_t)b * KK * MM + m0 + fr;
  ap[(size_t)kk * MM] = f2bf(a0 * inv);
}

// ---------------------------------------------------------------------------
// K2: vlad GEMM, fine-split (r6): grid (16 dc, 64 b) = 1024 blocks, 4/CU.
// Unchanged from r6.
// ---------------------------------------------------------------------------
__global__ __launch_bounds__(256, 4) void k_vlad(const float* __restrict__ x,
    const int* __restrict__ lengths, const float* __restrict__ Cc,
    const short* __restrict__ aT, const float* __restrict__ asum_p,
    float* __restrict__ out, float* __restrict__ ssq_part) {
  const int t = threadIdx.x, wv = t >> 6, lane = t & 63;
  const int l15 = lane & 15, quad = lane >> 4;
  const int dc = blockIdx.x, b = blockIdx.y;
  const int dh = wv & 1, mh = wv >> 1;
  const int dwb = dc * 128 + dh * 64;   // wave d-base (64 wide)
  const int mb  = mh * 64;              // wave m-base (64 frames)
  const int len = lengths[b];

  __shared__ __attribute__((aligned(16))) char ubuf[20480];
  short (*xbt)[64][40]     = (short(*)[64][40])ubuf;      // [wv][d-loc][m-slot]
  float (*exch)[2][64][20] = (float(*)[2][64][20])ubuf;   // [dh][writer mh][lane][16+pad]
  __shared__ float  asl[KK];
  __shared__ float4 avp[2][16];         // [dh][l15] avg partial of mh=1
  __shared__ float  ssw[4][17];         // [wv][k-local]

  if (t < KK) {
    float s = 0.f;
    #pragma unroll
    for (int p = 0; p < 8; ++p) s += asum_p[(size_t)(b * 8 + p) * KK + t];
    asl[t] = s;
  }

  const float* xb  = x  + (size_t)b * MM * DDIM;
  const short* at0 = aT + (size_t)b * KK * MM + l15 * MM + mb + quad * 8;

  const int q4   = l15 * 4;             // lane's 4 staged d-rows
  const int mrow = quad * 2;            // even m within pass group
  const int keyw = l15 & 3;             // store swizzle key
  const int keyr = (l15 >> 2) & 3;      // read swizzle key

  // ---- preload A-frags (L2-hot) ----
  bf16x8 A0[2], A1[2];
  #pragma unroll
  for (int ms = 0; ms < 2; ++ms) {
    A0[ms] = *(const bf16x8*)(at0 + ms * 32);
    A1[ms] = *(const bf16x8*)(at0 + 16 * MM + ms * 32);
  }

  // ---- preload all x (16 independent float4 loads in flight, masked) ----
  float4 v0[8], v1[8];
  #pragma unroll
  for (int ms = 0; ms < 2; ++ms) {
    #pragma unroll
    for (int p = 0; p < 4; ++p) {
      const int m = mb + ms * 32 + p * 8 + mrow;
      const float* xr = xb + (size_t)m * DDIM + dwb + q4;
      v0[ms * 4 + p] = (m < len) ? *(const float4*)xr
                                 : make_float4(0.f, 0.f, 0.f, 0.f);
      v1[ms * 4 + p] = (m + 1 < len) ? *(const float4*)(xr + DDIM)
                                     : make_float4(0.f, 0.f, 0.f, 0.f);
    }
  }

  // avgpool partial over this wave's m-half (zero-fill makes masking free)
  float avg[4] = {0.f, 0.f, 0.f, 0.f};
  #pragma unroll
  for (int i = 0; i < 8; ++i) {
    avg[0] += v0[i].x + v1[i].x;
    avg[1] += v0[i].y + v1[i].y;
    avg[2] += v0[i].z + v1[i].z;
    avg[3] += v0[i].w + v1[i].w;
  }
  #pragma unroll
  for (int c = 0; c < 4; ++c) {
    avg[c] += __shfl_xor(avg[c], 16, 64);
    avg[c] += __shfl_xor(avg[c], 32, 64);
  }
  if (mh == 1 && quad == 0)
    avp[dh][l15] = make_float4(avg[0], avg[1], avg[2], avg[3]);

  f32x4 acc0[4], acc1[4];
  #pragma unroll
  for (int nt = 0; nt < 4; ++nt) {
    acc0[nt] = (f32x4){0.f, 0.f, 0.f, 0.f};
    acc1[nt] = (f32x4){0.f, 0.f, 0.f, 0.f};
  }

  #pragma unroll
  for (int ms = 0; ms < 2; ++ms) {
    #pragma unroll
    for (int p = 0; p < 4; ++p) {
      const int i = ms * 4 + p;
      const int mls = (p ^ keyw) * 8 + mrow;  // swizzled m-slot
      *(unsigned*)&xbt[wv][q4 + 0][mls] = pack2(v0[i].x, v1[i].x);
      *(unsigned*)&xbt[wv][q4 + 1][mls] = pack2(v0[i].y, v1[i].y);
      *(unsigned*)&xbt[wv][q4 + 2][mls] = pack2(v0[i].z, v1[i].z);
      *(unsigned*)&xbt[wv][q4 + 3][mls] = pack2(v0[i].w, v1[i].w);
    }
    // wave-private tile: same-wave DS ordering is program order
    #pragma unroll
    for (int nt = 0; nt < 4; ++nt) {
      bf16x8 B = *(const bf16x8*)&xbt[wv][nt * 16 + l15][(quad ^ keyr) * 8];
      acc0[nt] = __builtin_amdgcn_mfma_f32_16x16x32_bf16(A0[ms], B, acc0[nt], 0, 0, 0);
      acc1[nt] = __builtin_amdgcn_mfma_f32_16x16x32_bf16(A1[ms], B, acc1[nt], 0, 0, 0);
    }
  }

  // wave-uniform k-split: keep kt==mh, donate the other half
  f32x4 keep[4], give[4];
  if (mh == 0) {
    #pragma unroll
    for (int nt = 0; nt < 4; ++nt) { keep[nt] = acc0[nt]; give[nt] = acc1[nt]; }
  } else {
    #pragma unroll
    for (int nt = 0; nt < 4; ++nt) { keep[nt] = acc1[nt]; give[nt] = acc0[nt]; }
  }

  __syncthreads();   // all xbt reads done (union safe); avp, asl visible
  #pragma unroll
  for (int nt = 0; nt < 4; ++nt)
    *(f32x4*)&exch[dh][mh][lane][nt * 4] = give[nt];

  // avgpool finish (mh=0 waves own the write)
  if (mh == 0 && quad == 0) {
    float4 pa = avp[dh][l15];
    float rl = 1.f / (float)len;
    *(float4*)(out + (size_t)b * OUTROW + dwb + q4) =
        make_float4((avg[0] + pa.x) * rl, (avg[1] + pa.y) * rl,
                    (avg[2] + pa.z) * rl, (avg[3] + pa.w) * rl);
  }

  __syncthreads();   // exch stores visible
  #pragma unroll
  for (int nt = 0; nt < 4; ++nt)
    keep[nt] += *(const f32x4*)&exch[dh][1 - mh][lane][nt * 4];

  // residual + ssq for this wave's 16 k x 64 d
  float* orow = out + (size_t)b * OUTROW + DDIM;
  #pragma unroll
  for (int r = 0; r < 4; ++r) {
    const int k = mh * 16 + quad * 4 + r;
    const float as = asl[k];
    float sqv = 0.f;
    #pragma unroll
    for (int nt = 0; nt < 4; ++nt) {
      const int d = dwb + nt * 16 + l15;
      float v = keep[nt][r] - as * Cc[(size_t)k * DDIM + d];
      orow[(size_t)k * DDIM + d] = v;
      sqv = fmaf(v, v, sqv);
    }
    sqv += __shfl_xor(sqv, 1, 64);
    sqv += __shfl_xor(sqv, 2, 64);
    sqv += __shfl_xor(sqv, 4, 64);
    sqv += __shfl_xor(sqv, 8, 64);
    if (l15 == 0) ssw[wv][quad * 4 + r] = sqv;
  }
  __syncthreads();
  if (t < KK) {
    const int mt = t >> 4, kl = t & 15;   // waves mt*2 and mt*2+1 hold k=t
    ssq_part[((size_t)dc * BB + b) * KK + t] = ssw[mt * 2][kl] + ssw[mt * 2 + 1][kl];
  }
}

// ---------------------------------------------------------------------------
// K3: fused scales + apply. grid (32 k, 64 b) x 256. NDC=16 partials.
// ---------------------------------------------------------------------------
__global__ __launch_bounds__(256) void k_norm(const float* __restrict__ ssq_part,
    float* __restrict__ out) {
  const int t = threadIdx.x;
  const int k = blockIdx.x;
  const int b = blockIdx.y;
  __shared__ float ssk[32];
  if (t < 32) {
    float sk = 0.f;
    #pragma unroll
    for (int dc = 0; dc < NDC; ++dc)
      sk += ssq_part[((size_t)dc * BB + b) * KK + t];
    ssk[t] = sk;
  }
  __syncthreads();
  float gss = 0.f, iv_own = 0.f;
  #pragma unroll
  for (int kk = 0; kk < 32; ++kk) {
    float nk = sqrtf(ssk[kk]);
    float iv = 1.f / fmaxf(nk, 1e-12f);
    float nn = nk * iv;
    gss += nn * nn;
    if (kk == k) iv_own = iv;
  }
  float sc = iv_own / fmaxf(sqrtf(gss), 1e-12f);
  float* row = out + (size_t)b * OUTROW + DDIM + (size_t)k * DDIM;
  #pragma unroll
  for (int h = 0; h < 2; ++h) {
    float4* p = (float4*)(row + h * 1024 + t * 4);
    float4 v = *p;
    v.x *= sc; v.y *= sc; v.z *= sc; v.w *= sc;
    *p = v;
  }
}

// ---------------------------------------------------------------------------
extern "C" void kernel_launch(void* const* d_in, const int* in_sizes, int n_in,
                              void* d_out, int out_size, void* d_ws, size_t ws_size,
                              hipStream_t stream) {
  const float* x       = (const float*)d_in[0];
  const int*   lengths = (const int*)d_in[1];
  const float* W       = (const float*)d_in[2];
  const float* C       = (const float*)d_in[3];
  float* out = (float*)d_out;

  short* Wb     = (short*)d_ws;                          // 32*2048 shorts
  short* aT     = Wb + (size_t)KK * DDIM;                // 64*32*128 shorts
  float* asum_p = (float*)(aT + (size_t)BB * KK * MM);   // 512*32 floats
  float* ssqp   = asum_p + (size_t)512 * KK;             // 16*64*32 floats

  k_prep  <<<dim3(32),      256, 0, stream>>>(W, Wb);
  k_logits<<<dim3(512),     512, 0, stream>>>(x, lengths, Wb, aT, asum_p);
  k_vlad  <<<dim3(NDC, BB), 256, 0, stream>>>(x, lengths, C, aT, asum_p, out, ssqp);
  k_norm  <<<dim3(KK, BB),  256, 0, stream>>>(ssqp, out);
}

// Round 11
// 139.355 us; speedup vs baseline: 1.1348x; 1.0266x over previous
//
#include <hip/hip_runtime.h>
#include <math.h>

#define BB 64
#define MM 128
#define DDIM 2048
#define KK 32
#define NDC 16                   // d-chunks for k_vlad (128-wide each)
#define OUTROW (DDIM + KK*DDIM)  // 67584

typedef __attribute__((ext_vector_type(8))) short bf16x8;
typedef __attribute__((ext_vector_type(4))) float f32x4;

// float -> bf16 RNE (inputs finite; no NaN handling needed)
__device__ __forceinline__ short f2bf(float f) {
  unsigned u = __builtin_bit_cast(unsigned, f);
  u += 0x7fffu + ((u >> 16) & 1u);
  return (short)(u >> 16);
}
__device__ __forceinline__ unsigned pack2(float lo, float hi) {
  return (unsigned)(unsigned short)f2bf(lo) | ((unsigned)(unsigned short)f2bf(hi) << 16);
}

// ---------------------------------------------------------------------------
// K1: fused logits GEMM + ssq + softmax + mask — COALESCED.
// r10/r11: r8 counters showed k_logits at 700 GB/s vs fillBuffer's 6300:
// the old direct loads put lane=row -> 64 scattered 16B txns per
// instruction (txn-rate-bound; why r9's extra waves were neutral). Now x
// and W are staged through LDS with row-major cooperative loads (512B
// contiguous runs), fp32->bf16 in-register; MFMA A/B frags read from LDS.
// Row pad 520 bf16 -> 8-lane bank-groups = minimum-cycle reads. W is read
// fp32 directly (k_prep + Wb eliminated; W is L2/L3-resident across
// blocks). MFMA math unchanged -> same absmax.
// Grid 512 x 256; block = 16 frames; 4 waves each own 128 d per 512-chunk.
// ---------------------------------------------------------------------------
__global__ __launch_bounds__(256, 2) void k_logits(const float* __restrict__ x,
    const int* __restrict__ lengths, const float* __restrict__ W,
    short* __restrict__ aT, float* __restrict__ asum_p) {
  const int t = threadIdx.x, wv = t >> 6, lane = t & 63;
  const int l15 = lane & 15, quad = lane >> 4;
  const int fg = blockIdx.x;           // 0..511
  const int g0 = fg * 16;              // first frame of block
  const int b  = fg >> 3;              // 8 blocks per batch
  const int m0 = (fg & 7) * 16;        // frame offset within batch
  const int len = lengths[b];

  if (m0 >= len) {
    // fully-invalid frame group: a == 0 -> write zeros directly, exit.
    if (t < KK) asum_p[(size_t)fg * KK + t] = 0.f;
    const int zk = t >> 3, zoff = (t & 7) * 2;   // 32 k x 16 m = 1024B
    *(unsigned*)(aT + (size_t)b * KK * MM + (size_t)zk * MM + m0 + zoff) = 0u;
    return;
  }

  __shared__ short xs[16][520];        // frame rows, pad->conflict-free
  __shared__ short ws[32][520];        // cluster rows
  __shared__ float sqf[16];
  __shared__ float lg[4][16][33];

  // x staging map: row = t>>4 (frame), 16 threads/row, 32B/thread/pass
  const int xr = t >> 4;
  const int xc = (t & 15) * 8;
  const bool rv = (m0 + xr) < len;
  const float* xrow = x + (size_t)(g0 + xr) * DDIM;
  // W staging map: row = t>>3 (cluster), 8 threads/row
  const int wr = t >> 3;
  const int wc = (t & 7) * 8;
  const float* wrow = W + (size_t)wr * DDIM;

  float ssq = 0.f;                     // frame xr partial over this thread's cols
  f32x4 c0 = {0.f, 0.f, 0.f, 0.f}, c1 = {0.f, 0.f, 0.f, 0.f};

  #pragma unroll
  for (int h = 0; h < 4; ++h) {        // d-chunk [h*512, h*512+512)
    const int d0 = h * 512;
    // ---- stage x chunk (coalesced 512B runs), ssq on the fly ----
    #pragma unroll
    for (int p = 0; p < 4; ++p) {
      const int col = p * 128 + xc;
      float4 a, c;
      if (rv) {
        a = *(const float4*)(xrow + d0 + col);
        c = *(const float4*)(xrow + d0 + col + 4);
      } else {
        a = make_float4(0.f, 0.f, 0.f, 0.f);
        c = make_float4(0.f, 0.f, 0.f, 0.f);
      }
      ssq = fmaf(a.x, a.x, ssq); ssq = fmaf(a.y, a.y, ssq);
      ssq = fmaf(a.z, a.z, ssq); ssq = fmaf(a.w, a.w, ssq);
      ssq = fmaf(c.x, c.x, ssq); ssq = fmaf(c.y, c.y, ssq);
      ssq = fmaf(c.z, c.z, ssq); ssq = fmaf(c.w, c.w, ssq);
      bf16x8 o = {f2bf(a.x), f2bf(a.y), f2bf(a.z), f2bf(a.w),
                  f2bf(c.x), f2bf(c.y), f2bf(c.z), f2bf(c.w)};
      *(bf16x8*)&xs[xr][col] = o;
    }
    // ---- stage W chunk (coalesced 256B runs), fp32->bf16 ----
    #pragma unroll
    for (int p = 0; p < 8; ++p) {
      const int col = p * 64 + wc;
      float4 a = *(const float4*)(wrow + d0 + col);
      float4 c = *(const float4*)(wrow + d0 + col + 4);
      bf16x8 o = {f2bf(a.x), f2bf(a.y), f2bf(a.z), f2bf(a.w),
                  f2bf(c.x), f2bf(c.y), f2bf(c.z), f2bf(c.w)};
      *(bf16x8*)&ws[wr][col] = o;
    }
    __syncthreads();
    // ---- MFMA: wave wv owns d-subrange [wv*128, wv*128+128) of chunk ----
    #pragma unroll
    for (int s = 0; s < 4; ++s) {
      const int off = wv * 128 + s * 32 + quad * 8;
      bf16x8 A  = *(const bf16x8*)&xs[l15][off];
      bf16x8 B0 = *(const bf16x8*)&ws[l15][off];
      bf16x8 B1 = *(const bf16x8*)&ws[16 + l15][off];
      c0 = __builtin_amdgcn_mfma_f32_16x16x32_bf16(A, B0, c0, 0, 0, 0);
      c1 = __builtin_amdgcn_mfma_f32_16x16x32_bf16(A, B1, c1, 0, 0, 0);
    }
    __syncthreads();                   // xs/ws reusable next chunk
  }

  // ssq: reduce across the 16 threads of each frame row (aligned 16-lane grp)
  ssq += __shfl_xor(ssq, 1, 64);
  ssq += __shfl_xor(ssq, 2, 64);
  ssq += __shfl_xor(ssq, 4, 64);
  ssq += __shfl_xor(ssq, 8, 64);
  if ((lane & 15) == 0) sqf[xr] = ssq;
  // C layout: row(frame) = quad*4+reg, col(k) = l15
  #pragma unroll
  for (int r = 0; r < 4; ++r) {
    lg[wv][quad * 4 + r][l15]      = c0[r];
    lg[wv][quad * 4 + r][16 + l15] = c1[r];
  }
  __syncthreads();

  // 16 threads per frame, 2 clusters each
  const int fr = t >> 4, kk = (t & 15) * 2;
  float s0 = 0.f, s1 = 0.f;
  #pragma unroll
  for (int w = 0; w < 4; ++w) { s0 += lg[w][fr][kk]; s1 += lg[w][fr][kk + 1]; }
  float ss  = sqf[fr];
  float inv = 1.f / fmaxf(sqrtf(ss), 1e-12f);
  s0 *= inv; s1 *= inv;
  float mx = fmaxf(s0, s1);
  mx = fmaxf(mx, __shfl_xor(mx, 1, 64));
  mx = fmaxf(mx, __shfl_xor(mx, 2, 64));
  mx = fmaxf(mx, __shfl_xor(mx, 4, 64));
  mx = fmaxf(mx, __shfl_xor(mx, 8, 64));
  float e0 = __expf(s0 - mx), e1 = __expf(s1 - mx);
  float se = e0 + e1;
  se += __shfl_xor(se, 1, 64);
  se += __shfl_xor(se, 2, 64);
  se += __shfl_xor(se, 4, 64);
  se += __shfl_xor(se, 8, 64);
  const bool valid = (m0 + fr) < len;
  float rr = valid ? (1.f / se) : 0.f;
  float a0 = e0 * rr, a1 = e1 * rr;

  __syncthreads();                    // done reading lg; reuse for asum
  lg[0][fr][kk] = a0; lg[0][fr][kk + 1] = a1;
  __syncthreads();
  if (t < KK) {
    float s = 0.f;
    #pragma unroll
    for (int f = 0; f < 16; ++f) s += lg[0][f][t];
    asum_p[(size_t)fg * KK + t] = s;
  }
  // a' = a * invn, transposed store [b][k][m]
  short* ap = aT + (size_t)b * KK * MM + m0 + fr;
  ap[(size_t)kk * MM]       = f2bf(a0 * inv);
  ap[(size_t)(kk + 1) * MM] = f2bf(a1 * inv);
}

// ---------------------------------------------------------------------------
// K2: vlad GEMM, fine-split (r6): grid (16 dc, 64 b) = 1024 blocks, 4/CU.
// Unchanged.
// ---------------------------------------------------------------------------
__global__ __launch_bounds__(256, 4) void k_vlad(const float* __restrict__ x,
    const int* __restrict__ lengths, const float* __restrict__ Cc,
    const short* __restrict__ aT, const float* __restrict__ asum_p,
    float* __restrict__ out, float* __restrict__ ssq_part) {
  const int t = threadIdx.x, wv = t >> 6, lane = t & 63;
  const int l15 = lane & 15, quad = lane >> 4;
  const int dc = blockIdx.x, b = blockIdx.y;
  const int dh = wv & 1, mh = wv >> 1;
  const int dwb = dc * 128 + dh * 64;   // wave d-base (64 wide)
  const int mb  = mh * 64;              // wave m-base (64 frames)
  const int len = lengths[b];

  __shared__ __attribute__((aligned(16))) char ubuf[20480];
  short (*xbt)[64][40]     = (short(*)[64][40])ubuf;      // [wv][d-loc][m-slot]
  float (*exch)[2][64][20] = (float(*)[2][64][20])ubuf;   // [dh][writer mh][lane][16+pad]
  __shared__ float  asl[KK];
  __shared__ float4 avp[2][16];         // [dh][l15] avg partial of mh=1
  __shared__ float  ssw[4][17];         // [wv][k-local]

  if (t < KK) {
    float s = 0.f;
    #pragma unroll
    for (int p = 0; p < 8; ++p) s += asum_p[(size_t)(b * 8 + p) * KK + t];
    asl[t] = s;
  }

  const float* xb  = x  + (size_t)b * MM * DDIM;
  const short* at0 = aT + (size_t)b * KK * MM + l15 * MM + mb + quad * 8;

  const int q4   = l15 * 4;             // lane's 4 staged d-rows
  const int mrow = quad * 2;            // even m within pass group
  const int keyw = l15 & 3;             // store swizzle key
  const int keyr = (l15 >> 2) & 3;      // read swizzle key

  // ---- preload A-frags (L2-hot) ----
  bf16x8 A0[2], A1[2];
  #pragma unroll
  for (int ms = 0; ms < 2; ++ms) {
    A0[ms] = *(const bf16x8*)(at0 + ms * 32);
    A1[ms] = *(const bf16x8*)(at0 + 16 * MM + ms * 32);
  }

  // ---- preload all x (16 independent float4 loads in flight, masked) ----
  float4 v0[8], v1[8];
  #pragma unroll
  for (int ms = 0; ms < 2; ++ms) {
    #pragma unroll
    for (int p = 0; p < 4; ++p) {
      const int m = mb + ms * 32 + p * 8 + mrow;
      const float* xr = xb + (size_t)m * DDIM + dwb + q4;
      v0[ms * 4 + p] = (m < len) ? *(const float4*)xr
                                 : make_float4(0.f, 0.f, 0.f, 0.f);
      v1[ms * 4 + p] = (m + 1 < len) ? *(const float4*)(xr + DDIM)
                                     : make_float4(0.f, 0.f, 0.f, 0.f);
    }
  }

  // avgpool partial over this wave's m-half (zero-fill makes masking free)
  float avg[4] = {0.f, 0.f, 0.f, 0.f};
  #pragma unroll
  for (int i = 0; i < 8; ++i) {
    avg[0] += v0[i].x + v1[i].x;
    avg[1] += v0[i].y + v1[i].y;
    avg[2] += v0[i].z + v1[i].z;
    avg[3] += v0[i].w + v1[i].w;
  }
  #pragma unroll
  for (int c = 0; c < 4; ++c) {
    avg[c] += __shfl_xor(avg[c], 16, 64);
    avg[c] += __shfl_xor(avg[c], 32, 64);
  }
  if (mh == 1 && quad == 0)
    avp[dh][l15] = make_float4(avg[0], avg[1], avg[2], avg[3]);

  f32x4 acc0[4], acc1[4];
  #pragma unroll
  for (int nt = 0; nt < 4; ++nt) {
    acc0[nt] = (f32x4){0.f, 0.f, 0.f, 0.f};
    acc1[nt] = (f32x4){0.f, 0.f, 0.f, 0.f};
  }

  #pragma unroll
  for (int ms = 0; ms < 2; ++ms) {
    #pragma unroll
    for (int p = 0; p < 4; ++p) {
      const int i = ms * 4 + p;
      const int mls = (p ^ keyw) * 8 + mrow;  // swizzled m-slot
      *(unsigned*)&xbt[wv][q4 + 0][mls] = pack2(v0[i].x, v1[i].x);
      *(unsigned*)&xbt[wv][q4 + 1][mls] = pack2(v0[i].y, v1[i].y);
      *(unsigned*)&xbt[wv][q4 + 2][mls] = pack2(v0[i].z, v1[i].z);
      *(unsigned*)&xbt[wv][q4 + 3][mls] = pack2(v0[i].w, v1[i].w);
    }
    // wave-private tile: same-wave DS ordering is program order
    #pragma unroll
    for (int nt = 0; nt < 4; ++nt) {
      bf16x8 B = *(const bf16x8*)&xbt[wv][nt * 16 + l15][(quad ^ keyr) * 8];
      acc0[nt] = __builtin_amdgcn_mfma_f32_16x16x32_bf16(A0[ms], B, acc0[nt], 0, 0, 0);
      acc1[nt] = __builtin_amdgcn_mfma_f32_16x16x32_bf16(A1[ms], B, acc1[nt], 0, 0, 0);
    }
  }

  // wave-uniform k-split: keep kt==mh, donate the other half
  f32x4 keep[4], give[4];
  if (mh == 0) {
    #pragma unroll
    for (int nt = 0; nt < 4; ++nt) { keep[nt] = acc0[nt]; give[nt] = acc1[nt]; }
  } else {
    #pragma unroll
    for (int nt = 0; nt < 4; ++nt) { keep[nt] = acc1[nt]; give[nt] = acc0[nt]; }
  }

  __syncthreads();   // all xbt reads done (union safe); avp, asl visible
  #pragma unroll
  for (int nt = 0; nt < 4; ++nt)
    *(f32x4*)&exch[dh][mh][lane][nt * 4] = give[nt];

  // avgpool finish (mh=0 waves own the write)
  if (mh == 0 && quad == 0) {
    float4 pa = avp[dh][l15];
    float rl = 1.f / (float)len;
    *(float4*)(out + (size_t)b * OUTROW + dwb + q4) =
        make_float4((avg[0] + pa.x) * rl, (avg[1] + pa.y) * rl,
                    (avg[2] + pa.z) * rl, (avg[3] + pa.w) * rl);
  }

  __syncthreads();   // exch stores visible
  #pragma unroll
  for (int nt = 0; nt < 4; ++nt)
    keep[nt] += *(const f32x4*)&exch[dh][1 - mh][lane][nt * 4];

  // residual + ssq for this wave's 16 k x 64 d
  float* orow = out + (size_t)b * OUTROW + DDIM;
  #pragma unroll
  for (int r = 0; r < 4; ++r) {
    const int k = mh * 16 + quad * 4 + r;
    const float as = asl[k];
    float sqv = 0.f;
    #pragma unroll
    for (int nt = 0; nt < 4; ++nt) {
      const int d = dwb + nt * 16 + l15;
      float v = keep[nt][r] - as * Cc[(size_t)k * DDIM + d];
      orow[(size_t)k * DDIM + d] = v;
      sqv = fmaf(v, v, sqv);
    }
    sqv += __shfl_xor(sqv, 1, 64);
    sqv += __shfl_xor(sqv, 2, 64);
    sqv += __shfl_xor(sqv, 4, 64);
    sqv += __shfl_xor(sqv, 8, 64);
    if (l15 == 0) ssw[wv][quad * 4 + r] = sqv;
  }
  __syncthreads();
  if (t < KK) {
    const int mt = t >> 4, kl = t & 15;   // waves mt*2 and mt*2+1 hold k=t
    ssq_part[((size_t)dc * BB + b) * KK + t] = ssw[mt * 2][kl] + ssw[mt * 2 + 1][kl];
  }
}

// ---------------------------------------------------------------------------
// K3: fused scales + apply. grid (32 k, 64 b) x 256. NDC=16 partials.
// ---------------------------------------------------------------------------
__global__ __launch_bounds__(256) void k_norm(const float* __restrict__ ssq_part,
    float* __restrict__ out) {
  const int t = threadIdx.x;
  const int k = blockIdx.x;
  const int b = blockIdx.y;
  __shared__ float ssk[32];
  if (t < 32) {
    float sk = 0.f;
    #pragma unroll
    for (int dc = 0; dc < NDC; ++dc)
      sk += ssq_part[((size_t)dc * BB + b) * KK + t];
    ssk[t] = sk;
  }
  __syncthreads();
  float gss = 0.f, iv_own = 0.f;
  #pragma unroll
  for (int kk = 0; kk < 32; ++kk) {
    float nk = sqrtf(ssk[kk]);
    float iv = 1.f / fmaxf(nk, 1e-12f);
    float nn = nk * iv;
    gss += nn * nn;
    if (kk == k) iv_own = iv;
  }
  float sc = iv_own / fmaxf(sqrtf(gss), 1e-12f);
  float* row = out + (size_t)b * OUTROW + DDIM + (size_t)k * DDIM;
  #pragma unroll
  for (int h = 0; h < 2; ++h) {
    float4* p = (float4*)(row + h * 1024 + t * 4);
    float4 v = *p;
    v.x *= sc; v.y *= sc; v.z *= sc; v.w *= sc;
    *p = v;
  }
}

// ---------------------------------------------------------------------------
extern "C" void kernel_launch(void* const* d_in, const int* in_sizes, int n_in,
                              void* d_out, int out_size, void* d_ws, size_t ws_size,
                              hipStream_t stream) {
  const float* x       = (const float*)d_in[0];
  const int*   lengths = (const int*)d_in[1];
  const float* W       = (const float*)d_in[2];
  const float* C       = (const float*)d_in[3];
  float* out = (float*)d_out;

  short* aT     = (short*)d_ws;                          // 64*32*128 shorts
  float* asum_p = (float*)(aT + (size_t)BB * KK * MM);   // 512*32 floats
  float* ssqp   = asum_p + (size_t)512 * KK;             // 16*64*32 floats

  k_logits<<<dim3(512),     256, 0, stream>>>(x, lengths, W, aT, asum_p);
  k_vlad  <<<dim3(NDC, BB), 256, 0, stream>>>(x, lengths, C, aT, asum_p, out, ssqp);
  k_norm  <<<dim3(KK, BB),  256, 0, stream>>>(ssqp, out);
}